// Round 1
// baseline (68.581 us; speedup 1.0000x reference)
//
#include <hip/hip_runtime.h>
#include <math.h>

// Problem shape (fixed by setup_inputs): B=8, S=4096, D=1024, CD=1024
// out = rmsnorm(x) * (1 + scale[b]) + shift[b], where [scale|shift] = cq @ wq^T + b_proj

constexpr int Bn = 8;
constexpr int Sn = 4096;
constexpr int Dn = 1024;
constexpr int TWO_D = 2048;
// ws layout in floats
constexpr int OFF_PART = 0;      // 2048 partials for |w| reduction
constexpr int OFF_MW   = 2048;   // 1 scalar: clipped mean(|w|)
constexpr int OFF_CQ   = 4096;   // 8192: quantized c (8 x 1024)
constexpr int OFF_SC   = 16384;  // 8192: 1 + scale (8 x 1024)
constexpr int OFF_SH   = 24576;  // 8192: shift (8 x 1024)

__device__ __forceinline__ float waveReduceSum(float v) {
#pragma unroll
    for (int off = 32; off > 0; off >>= 1) v += __shfl_down(v, off, 64);
    return v;
}
__device__ __forceinline__ float waveReduceMax(float v) {
#pragma unroll
    for (int off = 32; off > 0; off >>= 1) v = fmaxf(v, __shfl_down(v, off, 64));
    return v;
}

// 1) per-block partial sums of |w|; 2048 blocks x 256 threads x 4 elems = 2,097,152
__global__ void k_absw(const float* __restrict__ w, float* __restrict__ part) {
    int tid = threadIdx.x;
    size_t base = (size_t)blockIdx.x * 1024 + (size_t)tid * 4;
    float4 v = *(const float4*)(w + base);
    float s = fabsf(v.x) + fabsf(v.y) + fabsf(v.z) + fabsf(v.w);
    s = waveReduceSum(s);
    __shared__ float lds[4];
    if ((tid & 63) == 0) lds[tid >> 6] = s;
    __syncthreads();
    if (tid == 0) part[blockIdx.x] = lds[0] + lds[1] + lds[2] + lds[3];
}

// 2) finalize: mw = max(mean(|w|), EPS_Q)
__global__ void k_mw(const float* __restrict__ part, float* __restrict__ mw) {
    int tid = threadIdx.x;
    float s = 0.0f;
#pragma unroll
    for (int k = 0; k < 8; ++k) s += part[tid + k * 256];
    s = waveReduceSum(s);
    __shared__ float lds[4];
    if ((tid & 63) == 0) lds[tid >> 6] = s;
    __syncthreads();
    if (tid == 0) {
        float mean = (lds[0] + lds[1] + lds[2] + lds[3]) * (1.0f / 2097152.0f);
        mw[0] = fmaxf(mean, 1e-5f);
    }
}

// 3) activation quant of c: 8 blocks (one per batch) x 256 threads x 4 elems
__global__ void k_cq(const float* __restrict__ c, float* __restrict__ cq) {
    int b = blockIdx.x, tid = threadIdx.x;
    float4 v = ((const float4*)(c + (size_t)b * Dn))[tid];
    float m = fmaxf(fmaxf(fabsf(v.x), fabsf(v.y)), fmaxf(fabsf(v.z), fabsf(v.w)));
    m = waveReduceMax(m);
    __shared__ float lds[4];
    if ((tid & 63) == 0) lds[tid >> 6] = m;
    __syncthreads();
    float mx = fmaxf(fmaxf(lds[0], lds[1]), fmaxf(lds[2], lds[3]));
    float scale = 127.0f / fmaxf(mx, 1e-5f);
    float inv = 1.0f / scale;
    float4 q;
    q.x = fminf(fmaxf(rintf(v.x * scale), -128.0f), 127.0f) * inv;
    q.y = fminf(fmaxf(rintf(v.y * scale), -128.0f), 127.0f) * inv;
    q.z = fminf(fmaxf(rintf(v.z * scale), -128.0f), 127.0f) * inv;
    q.w = fminf(fmaxf(rintf(v.w * scale), -128.0f), 127.0f) * inv;
    ((float4*)(cq + (size_t)b * Dn))[tid] = q;
}

// 4) tiny GEMM: one wave per output row d (2048 waves), loop over b in registers.
//    wq[d][c] = clip(rint(w*1/mw), -1, 1) * mw ; emb = cq . wq + b_proj
__global__ void k_emb(const float* __restrict__ w, const float* __restrict__ bp,
                      const float* __restrict__ cq, const float* __restrict__ mwp,
                      float* __restrict__ sc, float* __restrict__ sh) {
    int tid = threadIdx.x;
    int lane = tid & 63;
    int d = (blockIdx.x * blockDim.x + tid) >> 6;   // 0..2047
    float mw = mwp[0];
    float sw = 1.0f / mw;
    const float* wr = w + (size_t)d * 1024 + (size_t)lane * 16;
    float t[16];
#pragma unroll
    for (int j = 0; j < 16; j += 4) {
        float4 v = *(const float4*)(wr + j);
        t[j + 0] = fminf(fmaxf(rintf(v.x * sw), -1.0f), 1.0f);
        t[j + 1] = fminf(fmaxf(rintf(v.y * sw), -1.0f), 1.0f);
        t[j + 2] = fminf(fmaxf(rintf(v.z * sw), -1.0f), 1.0f);
        t[j + 3] = fminf(fmaxf(rintf(v.w * sw), -1.0f), 1.0f);
    }
    for (int b = 0; b < Bn; ++b) {
        const float* cr = cq + (size_t)b * 1024 + (size_t)lane * 16;
        float dot = 0.0f;
#pragma unroll
        for (int j = 0; j < 16; j += 4) {
            float4 u = *(const float4*)(cr + j);
            dot += t[j + 0] * u.x + t[j + 1] * u.y + t[j + 2] * u.z + t[j + 3] * u.w;
        }
        dot = waveReduceSum(dot);
        if (lane == 0) {
            float val = dot * mw + bp[d];
            if (d < Dn) sc[b * Dn + d] = 1.0f + val;
            else        sh[b * Dn + (d - Dn)] = val;
        }
    }
}

// 5) main fused pass: one block per (b,s) row; 256 threads x float4
__global__ void k_main(const float* __restrict__ x, const float* __restrict__ rw,
                       const float* __restrict__ sc, const float* __restrict__ sh,
                       float* __restrict__ out) {
    int row = blockIdx.x;              // 0..32767
    int b = row >> 12;                 // row / 4096
    int tid = threadIdx.x;
    float4 v = ((const float4*)(x + (size_t)row * Dn))[tid];
    float ss = v.x * v.x + v.y * v.y + v.z * v.z + v.w * v.w;
    ss = waveReduceSum(ss);
    __shared__ float lds[4];
    if ((tid & 63) == 0) lds[tid >> 6] = ss;
    __syncthreads();
    float tot = lds[0] + lds[1] + lds[2] + lds[3];
    float inv = rsqrtf(tot * (1.0f / 1024.0f) + 1e-6f);
    float4 wv = ((const float4*)rw)[tid];
    float4 s1 = ((const float4*)(sc + (size_t)b * Dn))[tid];
    float4 s0 = ((const float4*)(sh + (size_t)b * Dn))[tid];
    float4 o;
    o.x = v.x * inv * wv.x * s1.x + s0.x;
    o.y = v.y * inv * wv.y * s1.y + s0.y;
    o.z = v.z * inv * wv.z * s1.z + s0.z;
    o.w = v.w * inv * wv.w * s1.w + s0.w;
    ((float4*)(out + (size_t)row * Dn))[tid] = o;
}

extern "C" void kernel_launch(void* const* d_in, const int* in_sizes, int n_in,
                              void* d_out, int out_size, void* d_ws, size_t ws_size,
                              hipStream_t stream) {
    const float* x  = (const float*)d_in[0];
    const float* c  = (const float*)d_in[1];
    const float* w  = (const float*)d_in[2];
    const float* bp = (const float*)d_in[3];
    const float* rw = (const float*)d_in[4];
    float* out = (float*)d_out;
    float* ws  = (float*)d_ws;

    float* part = ws + OFF_PART;
    float* mw   = ws + OFF_MW;
    float* cq   = ws + OFF_CQ;
    float* sc   = ws + OFF_SC;
    float* sh   = ws + OFF_SH;

    k_absw<<<TWO_D, 256, 0, stream>>>(w, part);
    k_mw  <<<1, 256, 0, stream>>>(part, mw);
    k_cq  <<<Bn, 256, 0, stream>>>(c, cq);
    k_emb <<<TWO_D / 4, 256, 0, stream>>>(w, bp, cq, mw, sc, sh);
    k_main<<<Bn * Sn, 256, 0, stream>>>(x, rw, sc, sh, out);
}

// Round 2
// 63.302 us; speedup vs baseline: 1.0834x; 1.0834x over previous
//
#include <hip/hip_runtime.h>
#include <math.h>

// Shape (fixed by setup_inputs): B=8, S=4096, D=1024, CD=1024
// out = rmsnorm(x) * (1 + scale[b]) + shift[b], [scale|shift] = cq @ wq^T + b_proj

constexpr int Bn = 8;
constexpr int Sn = 4096;
constexpr int Dn = 1024;
constexpr int TWO_D = 2048;
// ws layout (floats)
constexpr int OFF_PART = 0;      // 2048 partials for |w| reduction
constexpr int OFF_CQ   = 4096;   // 8192: quantized c (8 x 1024)
constexpr int OFF_SC   = 16384;  // 8192: 1 + scale (8 x 1024)
constexpr int OFF_SH   = 24576;  // 8192: shift (8 x 1024)

__device__ __forceinline__ float waveReduceSumBcast(float v) {
#pragma unroll
    for (int off = 32; off > 0; off >>= 1) v += __shfl_xor(v, off, 64);
    return v;   // all lanes hold the sum
}
__device__ __forceinline__ float waveReduceMaxBcast(float v) {
#pragma unroll
    for (int off = 32; off > 0; off >>= 1) v = fmaxf(v, __shfl_xor(v, off, 64));
    return v;
}

// 1) fused preamble: blocks 0..2047 -> |w| partial sums; blocks 2048..2055 -> c-quant
__global__ void k_pre(const float* __restrict__ w, const float* __restrict__ c,
                      float* __restrict__ part, float* __restrict__ cq) {
    int tid = threadIdx.x;
    if (blockIdx.x < TWO_D) {
        size_t base = (size_t)blockIdx.x * 1024 + (size_t)tid * 4;
        float4 v = *(const float4*)(w + base);
        float s = fabsf(v.x) + fabsf(v.y) + fabsf(v.z) + fabsf(v.w);
        s = waveReduceSumBcast(s);
        __shared__ float lds[4];
        if ((tid & 63) == 0) lds[tid >> 6] = s;
        __syncthreads();
        if (tid == 0) part[blockIdx.x] = lds[0] + lds[1] + lds[2] + lds[3];
    } else {
        int b = blockIdx.x - TWO_D;
        float4 v = ((const float4*)(c + (size_t)b * Dn))[tid];
        float m = fmaxf(fmaxf(fabsf(v.x), fabsf(v.y)), fmaxf(fabsf(v.z), fabsf(v.w)));
        m = waveReduceMaxBcast(m);
        __shared__ float lm[4];
        if ((tid & 63) == 0) lm[tid >> 6] = m;
        __syncthreads();
        float mx = fmaxf(fmaxf(lm[0], lm[1]), fmaxf(lm[2], lm[3]));
        float scale = 127.0f / fmaxf(mx, 1e-5f);
        float inv = 1.0f / scale;
        float4 q;
        q.x = fminf(fmaxf(rintf(v.x * scale), -128.0f), 127.0f) * inv;
        q.y = fminf(fmaxf(rintf(v.y * scale), -128.0f), 127.0f) * inv;
        q.z = fminf(fmaxf(rintf(v.z * scale), -128.0f), 127.0f) * inv;
        q.w = fminf(fmaxf(rintf(v.w * scale), -128.0f), 127.0f) * inv;
        ((float4*)(cq + (size_t)b * Dn))[tid] = q;
    }
}

// 2) tiny GEMM, mw folded in: each block first reduces part[2048] -> mw,
//    then one wave per output row d (512 blocks x 4 waves = 2048 waves).
__global__ void k_emb(const float* __restrict__ w, const float* __restrict__ bp,
                      const float* __restrict__ cq, const float* __restrict__ part,
                      float* __restrict__ sc, float* __restrict__ sh) {
    int tid = threadIdx.x;
    // block-wide reduce of partials -> mean(|w|)
    float s = 0.0f;
#pragma unroll
    for (int k = 0; k < 8; ++k) s += part[tid + k * 256];
    s = waveReduceSumBcast(s);
    __shared__ float lds[4];
    if ((tid & 63) == 0) lds[tid >> 6] = s;
    __syncthreads();
    float mw = fmaxf((lds[0] + lds[1] + lds[2] + lds[3]) * (1.0f / 2097152.0f), 1e-5f);
    float sw = 1.0f / mw;

    int lane = tid & 63;
    int d = (blockIdx.x * blockDim.x + tid) >> 6;   // 0..2047
    const float* wr = w + (size_t)d * 1024 + (size_t)lane * 16;
    float t[16];
#pragma unroll
    for (int j = 0; j < 16; j += 4) {
        float4 v = *(const float4*)(wr + j);
        t[j + 0] = fminf(fmaxf(rintf(v.x * sw), -1.0f), 1.0f);
        t[j + 1] = fminf(fmaxf(rintf(v.y * sw), -1.0f), 1.0f);
        t[j + 2] = fminf(fmaxf(rintf(v.z * sw), -1.0f), 1.0f);
        t[j + 3] = fminf(fmaxf(rintf(v.w * sw), -1.0f), 1.0f);
    }
    for (int b = 0; b < Bn; ++b) {
        const float* cr = cq + (size_t)b * 1024 + (size_t)lane * 16;
        float dot = 0.0f;
#pragma unroll
        for (int j = 0; j < 16; j += 4) {
            float4 u = *(const float4*)(cr + j);
            dot += t[j + 0] * u.x + t[j + 1] * u.y + t[j + 2] * u.z + t[j + 3] * u.w;
        }
        dot = waveReduceSumBcast(dot);
        if (lane == 0) {
            float val = dot * mw + bp[d];
            if (d < Dn) sc[b * Dn + d] = 1.0f + val;
            else        sh[b * Dn + (d - Dn)] = val;
        }
    }
}

// 3) main fused pass: one WAVE per (b,s) row; 4 rows per 256-thread block.
//    No LDS, no __syncthreads — butterfly reduce only.
__global__ void __launch_bounds__(256) k_main(
        const float* __restrict__ x, const float* __restrict__ rw,
        const float* __restrict__ sc, const float* __restrict__ sh,
        float* __restrict__ out) {
    int tid  = threadIdx.x;
    int lane = tid & 63;
    int row  = blockIdx.x * 4 + (tid >> 6);   // 0..32767
    int b    = row >> 12;                      // row / 4096

    const float4* xr = (const float4*)(x + (size_t)row * Dn);
    float4 v0 = xr[lane];
    float4 v1 = xr[lane + 64];
    float4 v2 = xr[lane + 128];
    float4 v3 = xr[lane + 192];

    float ss = v0.x*v0.x + v0.y*v0.y + v0.z*v0.z + v0.w*v0.w
             + v1.x*v1.x + v1.y*v1.y + v1.z*v1.z + v1.w*v1.w
             + v2.x*v2.x + v2.y*v2.y + v2.z*v2.z + v2.w*v2.w
             + v3.x*v3.x + v3.y*v3.y + v3.z*v3.z + v3.w*v3.w;
    ss = waveReduceSumBcast(ss);
    float inv = rsqrtf(ss * (1.0f / 1024.0f) + 1e-6f);

    const float4* rwv = (const float4*)rw;
    const float4* s1v = (const float4*)(sc + (size_t)b * Dn);
    const float4* s0v = (const float4*)(sh + (size_t)b * Dn);
    float4* ov = (float4*)(out + (size_t)row * Dn);

#pragma unroll
    for (int q = 0; q < 4; ++q) {
        int idx = lane + q * 64;
        float4 v = (q == 0) ? v0 : (q == 1) ? v1 : (q == 2) ? v2 : v3;
        float4 wv = rwv[idx];
        float4 s1 = s1v[idx];
        float4 s0 = s0v[idx];
        float4 o;
        o.x = v.x * inv * wv.x * s1.x + s0.x;
        o.y = v.y * inv * wv.y * s1.y + s0.y;
        o.z = v.z * inv * wv.z * s1.z + s0.z;
        o.w = v.w * inv * wv.w * s1.w + s0.w;
        ov[idx] = o;
    }
}

extern "C" void kernel_launch(void* const* d_in, const int* in_sizes, int n_in,
                              void* d_out, int out_size, void* d_ws, size_t ws_size,
                              hipStream_t stream) {
    const float* x  = (const float*)d_in[0];
    const float* c  = (const float*)d_in[1];
    const float* w  = (const float*)d_in[2];
    const float* bp = (const float*)d_in[3];
    const float* rw = (const float*)d_in[4];
    float* out = (float*)d_out;
    float* ws  = (float*)d_ws;

    float* part = ws + OFF_PART;
    float* cq   = ws + OFF_CQ;
    float* sc   = ws + OFF_SC;
    float* sh   = ws + OFF_SH;

    k_pre <<<TWO_D + Bn, 256, 0, stream>>>(w, c, part, cq);
    k_emb <<<TWO_D / 4, 256, 0, stream>>>(w, bp, cq, part, sc, sh);
    k_main<<<Bn * Sn / 4, 256, 0, stream>>>(x, rw, sc, sh, out);
}